// Round 4
// baseline (191.779 us; speedup 1.0000x reference)
//
#include <hip/hip_runtime.h>
#include <cstdint>

#define GH 10
#define GW 10

// Two lanes per sample: lane h=0 owns rows 0-4 (bitboard word "lo"),
// lane h=1 owns rows 5-9 (word "hi"). Pair communicates via __shfl_xor(.,1).
__global__ __launch_bounds__(256, 6) void custom_loss_kernel(
    const float* __restrict__ result,
    const int* __restrict__ points,
    float* __restrict__ out,
    int B)
{
    const int tid = blockIdx.x * blockDim.x + threadIdx.x;
    const int s = tid >> 1;        // sample
    const int h = tid & 1;         // half (0: rows 0-4, 1: rows 5-9)
    float loss = 0.f;
    if (s < B) {
        const float* __restrict__ r = result + (size_t)s * 100;
        const int4 p = ((const int4*)points)[s];
        const int p0y = p.x, p0x = p.y, p1y = p.z, p1x = p.w;
        const int dy0 = abs(p0y - p1y), dx0 = abs(p0x - p1x);
        const int base = dy0 + dx0;
        const int idx0 = p0y * GW + p0x;
        const int idx1 = p1y * GW + p1x;
        // point loads issued early (same line for both lanes of the pair)
        const float rs = r[idx0];
        const float re = r[idx1];

        float adxf[10];
        uint32_t inbox_m = 0;
#pragma unroll
        for (int x = 0; x < 10; ++x) {
            const int a = abs(x - p0x) + abs(x - p1x) - dx0;
            adxf[x] = (float)a;
            inbox_m |= (a == 0) ? (1u << x) : 0u;
        }

        // ---- pass 1 over own 5 rows ----
        const int ybase = 5 * h;
        const float* __restrict__ rh = r + ybase * 10;
        float sum_h = 0.f, sc_h = 0.f, box_h = 0.f;
        uint64_t mword = 0;                 // own 50-bit mask, bit = ylocal*10+x
#pragma unroll
        for (int i = 0; i < 5; ++i) {
            const int y = ybase + i;
            const float4 a4 = *(const float4*)(rh + i * 10);
            const float4 b4 = *(const float4*)(rh + i * 10 + 4);
            const float2 c2 = *(const float2*)(rh + i * 10 + 8);
            const float vv[10] = {a4.x, a4.y, a4.z, a4.w,
                                  b4.x, b4.y, b4.z, b4.w, c2.x, c2.y};
            const float rowacc = ((vv[0]+vv[1])+(vv[2]+vv[3])) +
                                 ((vv[4]+vv[5])+(vv[6]+vv[7])) + (vv[8]+vv[9]);
            sum_h += rowacc;
            const int ay = abs(y - p0y) + abs(y - p1y) - dy0;
            sc_h = fmaf((float)ay, rowacc, sc_h);
            float boxrow = 0.f;
            uint32_t rm = 0u;
#pragma unroll
            for (int x = 0; x < 10; ++x) {
                const float xv = vv[x];
                sc_h = fmaf(adxf[x], xv, sc_h);
                boxrow += ((inbox_m >> x) & 1u) ? xv : 0.f;
                // jnp.round half-to-even: for x in [0,1), round==1 <=> x>0.5
                rm |= (xv > 0.5f) ? (1u << x) : 0u;
            }
            box_h += (ay == 0) ? boxrow : 0.f;
            mword |= (uint64_t)rm << (10 * i);
        }
        const float sum_all = sum_h + __shfl_xor(sum_h, 1);
        const float sc      = sc_h  + __shfl_xor(sc_h, 1);
        const float boxSum  = box_h + __shfl_xor(box_h, 1);

        // ---- flood fill, split by word: each lane iterates its own 50 bits ----
        const uint64_t M50 = (1ull << 50) - 1;
        const uint64_t C0  = 0x10040100401ull;       // col-0 bit of each of 5 rows
        const uint64_t NC0 = M50 & ~C0;              // clear col0 after <<1
        const uint64_t NC9 = M50 & ~(C0 << 9);       // clear col9 after >>1
        uint64_t c = 0;                              // own cluster word
        if (h == 0) { if (idx0 <  50) c = 1ull << idx0; }
        else        { if (idx0 >= 50) c = 1ull << (idx0 - 50); }
#pragma unroll 1
        for (int it = 0; it < GH + GW; ++it) {       // monotone; early exit safe
            const uint64_t ho = c | ((c << 1) & NC0) | ((c >> 1) & NC9);
            const uint64_t hother =
                (uint64_t)__shfl_xor((unsigned long long)ho, 1);
            // seam: even needs odd's row5 shifted to bits 40-49; odd needs row4
            const uint64_t inc = h ? (hother >> 40) : ((hother & 0x3FFull) << 40);
            const uint64_t n = ((ho | (ho << 10) | (ho >> 10) | inc) & mword) | c;
            int ch = (n != c);
            ch |= __shfl_xor(ch, 1);
            c = n;
            if (!ch) break;
        }
        const int Kh = __popcll(c);
        const int K = Kh + __shfl_xor(Kh, 1);

        // exchange final words: both lanes get (clo, chi)
        const uint64_t c_other = (uint64_t)__shfl_xor((unsigned long long)c, 1);
        const uint64_t clo = h ? c_other : c;
        const uint64_t chi = h ? c : c_other;

        // ---- pass 2: re-read own 5 rows (L2/L3-warm), transposed-cluster sum ----
        // in_cl[y][x] = cluster[x][y] = bit (x*10+y); x<5 -> clo (b=x*10+y<50),
        // x>=5 -> chi. Pre-shift by 5h so per-cell shifts are constants.
        const uint64_t wlo = clo >> (5 * h);
        const uint64_t whi = chi >> (5 * h);
        float st_h = 0.f;
#pragma unroll
        for (int i = 0; i < 5; ++i) {
            const float4 a4 = *(const float4*)(rh + i * 10);
            const float4 b4 = *(const float4*)(rh + i * 10 + 4);
            const float2 c2 = *(const float2*)(rh + i * 10 + 8);
            const float vv[10] = {a4.x, a4.y, a4.z, a4.w,
                                  b4.x, b4.y, b4.z, b4.w, c2.x, c2.y};
#pragma unroll
            for (int x = 0; x < 10; ++x) {
                const uint64_t w = (x < 5) ? wlo : whi;
                const uint32_t bit = (uint32_t)((w >> ((x % 5) * 10 + i)) & 1ull);
                st_h = fmaf((float)bit, vv[x], st_h);
            }
        }
        const float S_T = st_h + __shfl_xor(st_h, 1);

        // ---- argmin over own rows of dist-to-end, first-flat-index ties ----
        int bestd = 1000, bidx = 0;
#pragma unroll
        for (int i = 0; i < 5; ++i) {
            const int y = ybase + i;
            const uint32_t rb = (uint32_t)((c >> (10 * i)) & 0x3FFull);
            const uint32_t left  = rb & ((2u << p1x) - 1);   // cols 0..p1x
            const uint32_t right = rb >> p1x;                // bit0 = col p1x
            const int dl = left  ? (p1x - (31 - __builtin_clz(left))) : 1000;
            const int dr = right ? __builtin_ctz(right) : 1000;
            int dx, xx;
            if (dl <= dr) { dx = dl; xx = p1x - dl; }        // tie -> smaller col
            else          { dx = dr; xx = p1x + dr; }
            const int d = abs(y - p1y) + dx;
            if (rb && d < bestd) { bestd = d; bidx = y * GW + xx; } // tie -> smaller row
        }
        {   // merge pair halves; tie -> smaller flat index
            const int od = __shfl_xor(bestd, 1);
            const int oi = __shfl_xor(bidx, 1);
            if (od < bestd || (od == bestd && oi < bidx)) { bestd = od; bidx = oi; }
        }

        // ---- epilogue: even lane only ----
        if (h == 0) {
            const bool better = bestd < base;
            const int ny = better ? bidx / 10 : p0y;
            const int nx = better ? bidx % 10 : p0x;
            const int gap = min(base, bestd);

            int by = ny, bx = nx, bg = gap;
            const int oy = p1y - ny, ox = p1x - nx;
            auto upd = [&](bool cond, int cy, int cx) {
                const int d = abs(cy - p1y) + abs(cx - p1x);
                if (cond && (d < bg)) { by = cy; bx = cx; bg = d; }
            };
            upd(ox < 0,                     ny,     nx - 1);
            upd((ox < 0) && (ny != 0),      ny - 1, nx - 1);
            upd((ox < 0) && (ny != GH - 1), ny + 1, nx - 1);
            upd(ox > 0,                     ny,     nx + 1);
            upd((ox > 0) && (ny != 0),      ny - 1, nx + 1);
            upd((ox > 0) && (ny != GH - 1), ny + 1, nx + 1);
            upd(oy < 0,                     ny - 1, nx);
            upd(oy > 0,                     ny + 1, nx);
            const int ncy = min(max(by, 0), GH - 1);
            const int ncx = min(max(bx, 0), GW - 1);
            const float rn = r[ncy * GW + ncx];          // single dependent load

            const float csf = (float)K;
            const float nboxf = (float)((dy0 + 1) * (dx0 + 1));
            const float loss_start = (2.f - (rs + re)) * 1000.f;
            const float lon = 5.f * csf + 15.f * sum_all - 20.f * S_T;
            const float single_cell = 0.5f * sc + 20.f * (nboxf - boxSum);
            const float cpen = 12.f * csf * S_T;
            const float gap_pen = (float)gap * 300.f * (1.f - rn);
            loss = loss_start + lon + single_cell + cpen + gap_pen;
        }
    }

    // ---- block reduction: wave shuffle -> LDS -> one atomic per block ----
#pragma unroll
    for (int off = 32; off > 0; off >>= 1)
        loss += __shfl_down(loss, off);
    __shared__ float wsum[4];
    const int lane = threadIdx.x & 63;
    const int wid = threadIdx.x >> 6;
    if (lane == 0) wsum[wid] = loss;
    __syncthreads();
    if (threadIdx.x == 0)
        atomicAdd(out, wsum[0] + wsum[1] + wsum[2] + wsum[3]);
}

extern "C" void kernel_launch(void* const* d_in, const int* in_sizes, int n_in,
                              void* d_out, int out_size, void* d_ws, size_t ws_size,
                              hipStream_t stream)
{
    const float* result = (const float*)d_in[0];
    const int* points   = (const int*)d_in[1];
    float* out = (float*)d_out;
    const int B = in_sizes[0] / 100;
    hipMemsetAsync(out, 0, sizeof(float), stream);   // harness poisons d_out with 0xAA
    const int block = 256;
    const int grid = (2 * B + block - 1) / block;    // 2 lanes per sample
    custom_loss_kernel<<<grid, block, 0, stream>>>(result, points, out, B);
}

// Round 5
// 181.916 us; speedup vs baseline: 1.0542x; 1.0542x over previous
//
#include <hip/hip_runtime.h>
#include <cstdint>

#define GH 10
#define GW 10

// Four lanes per sample. Lane q owns float4s {q, q+4, ..., q+20} (+ #24 for q==0),
// so each wave64 load instruction reads 16 fully-dense cache lines (4 lanes = 64 B).
// The whole sample stays in registers (25 floats/lane) -> no pass-2 re-read.
__global__ __launch_bounds__(256, 4) void custom_loss_kernel(
    const float* __restrict__ result,
    const int* __restrict__ points,
    float* __restrict__ out,
    int B)
{
    const int tid = blockIdx.x * blockDim.x + threadIdx.x;
    const int s = tid >> 2;      // sample
    const int q = tid & 3;       // quad lane
    float loss = 0.f;
    if (s < B) {
        const float* __restrict__ r = result + (size_t)s * 100;
        const int4 p = ((const int4*)points)[s];
        const int p0y = p.x, p0x = p.y, p1y = p.z, p1x = p.w;
        const int dy0 = abs(p0y - p1y), dx0 = abs(p0x - p1x);
        const int base0 = dy0 + dx0;
        const int idx0 = p0y * GW + p0x;
        const int idx1 = p1y * GW + p1x;
        const float rs = r[idx0];   // quad-uniform address -> broadcast coalesce
        const float re = r[idx1];

        // ---- coalesced quad loads ----
        float4 v4[7];
#pragma unroll
        for (int i = 0; i < 6; ++i) v4[i] = ((const float4*)r)[4 * i + q];
        v4[6] = make_float4(0.f, 0.f, 0.f, 0.f);
        if (q == 0) v4[6] = ((const float4*)r)[24];   // floats 96..99

        // ---- pass 1 over own 25 cells (coords computed arithmetically) ----
        const uint64_t M50 = (1ull << 50) - 1;
        float sum_p = 0.f, sc_p = 0.f, box_p = 0.f;
        uint64_t mlo = 0, mhi = 0;
#pragma unroll
        for (int i = 0; i < 7; ++i) {
            // base flat index of this float4; for i==6,q>0 it's >=100 but v==0
            const int kbase = (i < 6) ? 4 * (4 * i + q) : (96 + 4 * q);
            const float vv[4] = {v4[i].x, v4[i].y, v4[i].z, v4[i].w};
            uint32_t nib = 0;
#pragma unroll
            for (int j = 0; j < 4; ++j) {
                const int flat = kbase + j;
                const int y = (flat * 205) >> 11;      // flat/10 for 0..1023
                const int x = flat - 10 * y;
                const float v = vv[j];
                sum_p += v;
                const int af = abs(y - p0y) + abs(y - p1y) - dy0
                             + abs(x - p0x) + abs(x - p1x) - dx0;   // manhattan detour
                sc_p = fmaf((float)af, v, sc_p);
                box_p += (af == 0) ? v : 0.f;
                // jnp.round half-to-even: for v in [0,1), round==1 <=> v>0.5
                nib |= (v > 0.5f) ? (1u << j) : 0u;
            }
            // place 4-bit nibble at bit kbase of the 100-bit board (50+50 split)
            const uint64_t n64 = (uint64_t)nib;
            const int shhi = (kbase >= 50) ? (kbase - 50) : 0;
            mlo |= (kbase <= 44) ? (n64 << kbase)
                                 : ((kbase == 48) ? ((n64 & 3ull) << 48) : 0);
            mhi |= (kbase >= 52) ? (n64 << shhi)
                                 : ((kbase == 48) ? (n64 >> 2) : 0);
        }
        // quad merge (lanes differ only in q-bit pair -> xor 1, xor 2)
        sum_p += __shfl_xor(sum_p, 1); sum_p += __shfl_xor(sum_p, 2);
        sc_p  += __shfl_xor(sc_p, 1);  sc_p  += __shfl_xor(sc_p, 2);
        box_p += __shfl_xor(box_p, 1); box_p += __shfl_xor(box_p, 2);
        mlo |= (uint64_t)__shfl_xor((unsigned long long)mlo, 1);
        mlo |= (uint64_t)__shfl_xor((unsigned long long)mlo, 2);
        mhi |= (uint64_t)__shfl_xor((unsigned long long)mhi, 1);
        mhi |= (uint64_t)__shfl_xor((unsigned long long)mhi, 2);
        const float sum_all = sum_p, sc = sc_p, boxSum = box_p;

        // ---- 8-connected flood fill, <=20 single-step dilations (as reference) ----
        const uint64_t C0  = 0x10040100401ull;        // col-0 bit of each of 5 rows
        const uint64_t NC0 = M50 & ~C0;               // clear col0 after <<1
        const uint64_t NC9 = M50 & ~(C0 << 9);        // clear col9 after >>1
        uint64_t clo = 0, chi = 0;
        if (idx0 < 50) clo = 1ull << idx0; else chi = 1ull << (idx0 - 50);
#pragma unroll 1
        for (int it = 0; it < GH + GW; ++it) {        // monotone: early exit safe
            const uint64_t hlo = clo | ((clo << 1) & NC0) | ((clo >> 1) & NC9);
            const uint64_t hhi = chi | ((chi << 1) & NC0) | ((chi >> 1) & NC9);
            uint64_t nlo = (hlo | (hlo << 10) | (hlo >> 10) | ((hhi & 0x3FFull) << 40)) & mlo;
            uint64_t nhi = (hhi | (hhi << 10) | (hhi >> 10) | (hlo >> 40)) & mhi;
            nlo |= clo; nhi |= chi;
            if (nlo == clo && nhi == chi) break;
            clo = nlo; chi = nhi;
        }
        const int K = __popcll(clo) + __popcll(chi);

        // ---- S_T: transposed-cluster weighted sum over own cells (data in regs) ----
        float st_p = 0.f;
#pragma unroll
        for (int i = 0; i < 7; ++i) {
            const int kbase = (i < 6) ? 4 * (4 * i + q) : (96 + 4 * q);
            const float vv[4] = {v4[i].x, v4[i].y, v4[i].z, v4[i].w};
#pragma unroll
            for (int j = 0; j < 4; ++j) {
                const int flat = kbase + j;
                const int y = (flat * 205) >> 11;
                const int x = flat - 10 * y;
                const int tr = x * 10 + y;             // in_cl[y][x] = cluster[x][y]
                const int trs = (tr >= 50) ? (tr - 50) : tr;
                const uint64_t w = (tr >= 50) ? chi : clo;
                st_p = fmaf((float)((w >> trs) & 1ull), vv[j], st_p);
            }
        }
        st_p += __shfl_xor(st_p, 1); st_p += __shfl_xor(st_p, 2);
        const float S_T = st_p;

        // ---- argmin over cluster cells of dist-to-end, first-flat-index ties ----
        int bestd = 1000, bidx = 0;
#pragma unroll
        for (int y = 0; y < GH; ++y) {
            const uint32_t rb = (uint32_t)((y < 5 ? (clo >> (10 * y))
                                                  : (chi >> (10 * (y - 5)))) & 0x3FFull);
            const uint32_t left  = rb & ((2u << p1x) - 1);   // cols 0..p1x
            const uint32_t right = rb >> p1x;                // bit0 = col p1x
            const int dl = left  ? (p1x - (31 - __builtin_clz(left))) : 1000;
            const int dr = right ? __builtin_ctz(right) : 1000;
            int dx, xx;
            if (dl <= dr) { dx = dl; xx = p1x - dl; }        // tie -> smaller col
            else          { dx = dr; xx = p1x + dr; }
            const int d = abs(y - p1y) + dx;
            if (rb && d < bestd) { bestd = d; bidx = y * GW + xx; } // tie -> smaller row
        }

        // ---- epilogue (replicated across the quad; only q==0 contributes) ----
        const bool better = bestd < base0;
        const int ny = better ? bidx / 10 : p0y;
        const int nx = better ? bidx % 10 : p0x;
        const int gap = min(base0, bestd);

        int by = ny, bx = nx, bg = gap;
        const int oy = p1y - ny, ox = p1x - nx;
        auto upd = [&](bool cond, int cy, int cx) {
            const int d = abs(cy - p1y) + abs(cx - p1x);
            if (cond && (d < bg)) { by = cy; bx = cx; bg = d; }
        };
        upd(ox < 0,                     ny,     nx - 1);
        upd((ox < 0) && (ny != 0),      ny - 1, nx - 1);
        upd((ox < 0) && (ny != GH - 1), ny + 1, nx - 1);
        upd(ox > 0,                     ny,     nx + 1);
        upd((ox > 0) && (ny != 0),      ny - 1, nx + 1);
        upd((ox > 0) && (ny != GH - 1), ny + 1, nx + 1);
        upd(oy < 0,                     ny - 1, nx);
        upd(oy > 0,                     ny + 1, nx);
        const int ncy = min(max(by, 0), GH - 1);
        const int ncx = min(max(bx, 0), GW - 1);
        const float rn = r[ncy * GW + ncx];       // quad-uniform dependent load

        const float csf = (float)K;
        const float nboxf = (float)((dy0 + 1) * (dx0 + 1));
        const float loss_start = (2.f - (rs + re)) * 1000.f;
        const float lon = 5.f * csf + 15.f * sum_all - 20.f * S_T;
        const float single_cell = 0.5f * sc + 20.f * (nboxf - boxSum);
        const float cpen = 12.f * csf * S_T;
        const float gap_pen = (float)gap * 300.f * (1.f - rn);
        loss = loss_start + lon + single_cell + cpen + gap_pen;
        if (q != 0) loss = 0.f;                   // one contribution per sample
    }

    // ---- block reduction: wave shuffle -> LDS -> one atomic per block ----
#pragma unroll
    for (int off = 32; off > 0; off >>= 1)
        loss += __shfl_down(loss, off);
    __shared__ float wsum[4];
    const int lane = threadIdx.x & 63;
    const int wid = threadIdx.x >> 6;
    if (lane == 0) wsum[wid] = loss;
    __syncthreads();
    if (threadIdx.x == 0)
        atomicAdd(out, wsum[0] + wsum[1] + wsum[2] + wsum[3]);
}

extern "C" void kernel_launch(void* const* d_in, const int* in_sizes, int n_in,
                              void* d_out, int out_size, void* d_ws, size_t ws_size,
                              hipStream_t stream)
{
    const float* result = (const float*)d_in[0];
    const int* points   = (const int*)d_in[1];
    float* out = (float*)d_out;
    const int B = in_sizes[0] / 100;
    hipMemsetAsync(out, 0, sizeof(float), stream);   // harness poisons d_out with 0xAA
    const int block = 256;
    const int grid = (4 * B + block - 1) / block;    // 4 lanes per sample
    custom_loss_kernel<<<grid, block, 0, stream>>>(result, points, out, B);
}

// Round 6
// 180.209 us; speedup vs baseline: 1.0642x; 1.0095x over previous
//
#include <hip/hip_runtime.h>
#include <cstdint>

#define GH 10
#define GW 10

// Hybrid: dense coalesced global->LDS staging (round-5 memory pattern) +
// row-aligned 2-lanes-per-sample compute with compile-time x indexing
// (round-4 math, 3x fewer VALU ops/sample than coordinate arithmetic).
__global__ __launch_bounds__(256, 3) void custom_loss_kernel(
    const float* __restrict__ result,
    const int* __restrict__ points,
    float* __restrict__ out,
    int B)
{
    __shared__ float lds[128 * 100];          // 51.2 KB -> 3 blocks/CU
    const int tix = threadIdx.x;

    // ---- staging: 128 samples = 3200 float4, 256 threads, fully coalesced ----
    {
        const size_t base4 = (size_t)blockIdx.x * (128 * 25);
        const size_t total4 = (size_t)B * 25;
        float4* lds4 = (float4*)lds;
        const float4* g4 = (const float4*)result;
#pragma unroll
        for (int k = 0; k < 12; ++k) {
            const int off = k * 256 + tix;
            if (base4 + off < total4) lds4[off] = g4[base4 + off];
        }
        const int off = 12 * 256 + tix;       // remaining 128 float4s
        if (tix < 128 && base4 + off < total4) lds4[off] = g4[base4 + off];
    }
    __syncthreads();

    const int s_local = tix >> 1;             // sample within block
    const int h = tix & 1;                    // half: rows 5h..5h+4
    const int s = blockIdx.x * 128 + s_local;
    float loss = 0.f;
    if (s < B) {
        const float* __restrict__ sp = lds + s_local * 100;
        const int4 p = ((const int4*)points)[s];
        const int p0y = p.x, p0x = p.y, p1y = p.z, p1x = p.w;
        const int dy0 = abs(p0y - p1y), dx0 = abs(p0x - p1x);
        const int base0 = dy0 + dx0;
        const int idx0 = p0y * GW + p0x;
        const int idx1 = p1y * GW + p1x;
        const float rs = sp[idx0];            // LDS gather, cheap
        const float re = sp[idx1];

        float adxf[10], inboxf[10];           // compile-time indexed -> registers
#pragma unroll
        for (int x = 0; x < 10; ++x) {
            const int a = abs(x - p0x) + abs(x - p1x) - dx0;
            adxf[x] = (float)a;
            inboxf[x] = (a == 0) ? 1.f : 0.f;
        }

        // ---- read own 5 rows (50 floats) from LDS; keep in registers ----
        const float2* rp2 = (const float2*)(sp + h * 50);   // 8B-aligned always
        float vv[50];
#pragma unroll
        for (int i = 0; i < 25; ++i) {
            const float2 t = rp2[i];
            vv[2 * i] = t.x; vv[2 * i + 1] = t.y;
        }

        // ---- pass 1 over own rows ----
        float sum_h = 0.f, sc_h = 0.f, box_h = 0.f;
        uint64_t mword = 0;                   // own 50-bit mask, bit = i*10+x
#pragma unroll
        for (int i = 0; i < 5; ++i) {
            const int y = 5 * h + i;
            const float* v = vv + 10 * i;
            const float rowacc = ((v[0]+v[1])+(v[2]+v[3])) +
                                 ((v[4]+v[5])+(v[6]+v[7])) + (v[8]+v[9]);
            sum_h += rowacc;
            const int ay = abs(y - p0y) + abs(y - p1y) - dy0;
            sc_h = fmaf((float)ay, rowacc, sc_h);
            float boxrow = 0.f;
            uint32_t rm = 0u;
#pragma unroll
            for (int x = 0; x < 10; ++x) {
                sc_h = fmaf(adxf[x], v[x], sc_h);
                boxrow = fmaf(inboxf[x], v[x], boxrow);
                // jnp.round half-to-even: for v in [0,1), round==1 <=> v>0.5
                rm |= (v[x] > 0.5f) ? (1u << x) : 0u;
            }
            box_h += (ay == 0) ? boxrow : 0.f;
            mword |= (uint64_t)rm << (10 * i);
        }
        const float sum_all = sum_h + __shfl_xor(sum_h, 1);
        const float sc      = sc_h  + __shfl_xor(sc_h, 1);
        const float boxSum  = box_h + __shfl_xor(box_h, 1);
        const uint64_t mo = (uint64_t)__shfl_xor((unsigned long long)mword, 1);
        const uint64_t mlo = h ? mo : mword;
        const uint64_t mhi = h ? mword : mo;

        // ---- flood fill: full board per lane (no per-iter pair sync) ----
        const uint64_t M50 = (1ull << 50) - 1;
        const uint64_t C0  = 0x10040100401ull;        // col-0 bit of 5 rows
        const uint64_t NC0 = M50 & ~C0;
        const uint64_t NC9 = M50 & ~(C0 << 9);
        uint64_t clo = 0, chi = 0;
        if (idx0 < 50) clo = 1ull << idx0; else chi = 1ull << (idx0 - 50);
#pragma unroll 1
        for (int it = 0; it < GH + GW; ++it) {        // cap 20 = reference; early
            const uint64_t hlo = clo | ((clo << 1) & NC0) | ((clo >> 1) & NC9);
            const uint64_t hhi = chi | ((chi << 1) & NC0) | ((chi >> 1) & NC9);
            uint64_t nlo = (hlo | (hlo << 10) | (hlo >> 10) | ((hhi & 0x3FFull) << 40)) & mlo;
            uint64_t nhi = (hhi | (hhi << 10) | (hhi >> 10) | (hlo >> 40)) & mhi;
            nlo |= clo; nhi |= chi;
            if (nlo == clo && nhi == chi) break;      // exit only at fixpoint
            clo = nlo; chi = nhi;
        }
        const int K = __popcll(clo) + __popcll(chi);

        // ---- S_T over own cells (values still in registers) ----
        // in_cl[y][x] = cluster bit (x*10+y); y = 5h+i -> pre-shift words by 5h
        const uint64_t wlo = clo >> (5 * h);
        const uint64_t whi = chi >> (5 * h);
        float st_h = 0.f;
#pragma unroll
        for (int i = 0; i < 5; ++i) {
            const float* v = vv + 10 * i;
#pragma unroll
            for (int x = 0; x < 10; ++x) {
                const uint64_t w = (x < 5) ? wlo : whi;    // compile-time select
                const uint32_t bit = (uint32_t)((w >> ((x % 5) * 10 + i)) & 1ull);
                st_h = fmaf((float)bit, v[x], st_h);
            }
        }
        const float S_T = st_h + __shfl_xor(st_h, 1);

        // ---- argmin (own 5 rows, then pair merge; first-flat-index ties) ----
        int bestd = 1000, bidx = 0;
        const uint64_t cw = h ? chi : clo;
#pragma unroll
        for (int i = 0; i < 5; ++i) {
            const int y = 5 * h + i;
            const uint32_t rb = (uint32_t)((cw >> (10 * i)) & 0x3FFull);
            const uint32_t left  = rb & ((2u << p1x) - 1);
            const uint32_t right = rb >> p1x;
            const int dl = left  ? (p1x - (31 - __builtin_clz(left))) : 1000;
            const int dr = right ? __builtin_ctz(right) : 1000;
            int dx, xx;
            if (dl <= dr) { dx = dl; xx = p1x - dl; }      // tie -> smaller col
            else          { dx = dr; xx = p1x + dr; }
            const int d = abs(y - p1y) + dx;
            if (rb && d < bestd) { bestd = d; bidx = y * GW + xx; }
        }
        {   // pair merge; tie -> smaller flat index
            const int od = __shfl_xor(bestd, 1);
            const int oi = __shfl_xor(bidx, 1);
            if (od < bestd || (od == bestd && oi < bidx)) { bestd = od; bidx = oi; }
        }

        // ---- epilogue (replicated; only h==0 contributes) ----
        const bool better = bestd < base0;
        const int ny = better ? bidx / 10 : p0y;
        const int nx = better ? bidx % 10 : p0x;
        const int gap = min(base0, bestd);

        int by = ny, bx = nx, bg = gap;
        const int oy = p1y - ny, ox = p1x - nx;
        auto upd = [&](bool cond, int cy, int cx) {
            const int d = abs(cy - p1y) + abs(cx - p1x);
            if (cond && (d < bg)) { by = cy; bx = cx; bg = d; }
        };
        upd(ox < 0,                     ny,     nx - 1);
        upd((ox < 0) && (ny != 0),      ny - 1, nx - 1);
        upd((ox < 0) && (ny != GH - 1), ny + 1, nx - 1);
        upd(ox > 0,                     ny,     nx + 1);
        upd((ox > 0) && (ny != 0),      ny - 1, nx + 1);
        upd((ox > 0) && (ny != GH - 1), ny + 1, nx + 1);
        upd(oy < 0,                     ny - 1, nx);
        upd(oy > 0,                     ny + 1, nx);
        const int ncy = min(max(by, 0), GH - 1);
        const int ncx = min(max(bx, 0), GW - 1);
        const float rn = sp[ncy * GW + ncx];      // LDS gather, no HBM round trip

        const float csf = (float)K;
        const float nboxf = (float)((dy0 + 1) * (dx0 + 1));
        const float loss_start = (2.f - (rs + re)) * 1000.f;
        const float lon = 5.f * csf + 15.f * sum_all - 20.f * S_T;
        const float single_cell = 0.5f * sc + 20.f * (nboxf - boxSum);
        const float cpen = 12.f * csf * S_T;
        const float gap_pen = (float)gap * 300.f * (1.f - rn);
        loss = loss_start + lon + single_cell + cpen + gap_pen;
        if (h != 0) loss = 0.f;                   // one contribution per sample
    }

    // ---- block reduction: wave shuffle -> LDS -> one atomic per block ----
#pragma unroll
    for (int off = 32; off > 0; off >>= 1)
        loss += __shfl_down(loss, off);
    __shared__ float wsum[4];
    const int lane = threadIdx.x & 63;
    const int wid = threadIdx.x >> 6;
    if (lane == 0) wsum[wid] = loss;
    __syncthreads();
    if (threadIdx.x == 0)
        atomicAdd(out, wsum[0] + wsum[1] + wsum[2] + wsum[3]);
}

extern "C" void kernel_launch(void* const* d_in, const int* in_sizes, int n_in,
                              void* d_out, int out_size, void* d_ws, size_t ws_size,
                              hipStream_t stream)
{
    const float* result = (const float*)d_in[0];
    const int* points   = (const int*)d_in[1];
    float* out = (float*)d_out;
    const int B = in_sizes[0] / 100;
    hipMemsetAsync(out, 0, sizeof(float), stream);   // harness poisons d_out with 0xAA
    const int block = 256;                            // 128 samples per block
    const int grid = (2 * B + block - 1) / block;
    custom_loss_kernel<<<grid, block, 0, stream>>>(result, points, out, B);
}